// Round 11
// baseline (688.414 us; speedup 1.0000x reference)
//
#include <hip/hip_runtime.h>

// SR-GNN session model, MI355X (gfx950). Inputs fp32/int32, output fp32.
// r11 (split-measuring round): session3 (r10, verbatim) + score3 (r9,
// verbatim) + score4 (new). score4 overwrites score3's output with identical
// arithmetic -> total - 407us == score4's cost, decoded exactly.
// score4: 32-row b-tiles (2x staging amortization vs score3), per-row
// immediate stores (no acc array, ~60 VGPR), fully unrolled row loop so
// independent per-row s_load chains pipeline.
//
// ws layout: [0) s_g fp32 : 4096 x 32 f32  (512 KB)

#define B_BATCH 4096
#define N_NODE  16
#define L_SEQ   20
#define D_DIM   32
#define NV_OUT  49999

typedef float f32x4 __attribute__((ext_vector_type(4)));

__device__ __forceinline__ float sigf(float x) {
    return 1.0f / (1.0f + __expf(-x));
}

// ---------------------------------------------------------------- kernel 1
// One block per session; 256 threads = 8 node-groups x 32 d-lanes.
// VERBATIM r10 session3.
__global__ __launch_bounds__(256) void session3_kernel(
    const int*   __restrict__ alias_inputs,  // [B,20]
    const float* __restrict__ A,             // [B,16,32]
    const int*   __restrict__ items,         // [B,16]
    const int*   __restrict__ mask,          // [B,20]
    const float* __restrict__ emb,           // [V,32]
    const float* __restrict__ w_ih,          // [96,64]
    const float* __restrict__ w_hh,          // [96,32]
    const float* __restrict__ b_ih, const float* __restrict__ b_hh,
    const float* __restrict__ b_iah, const float* __restrict__ b_oah,
    const float* __restrict__ w_ein, const float* __restrict__ b_ein,
    const float* __restrict__ w_eout, const float* __restrict__ b_eout,
    const float* __restrict__ w1, const float* __restrict__ b1,
    const float* __restrict__ w2, const float* __restrict__ b2,
    const float* __restrict__ w3,
    float* __restrict__ sg_out)              // [B,32] fp32 (ws)
{
    const int b   = blockIdx.x;
    const int tid = threadIdx.x;
    const int g   = tid >> 5;      // node group 0..7
    const int d   = tid & 31;      // feature column
    const int n0  = g, n1 = g + 8;

    __shared__ float h_s [N_NODE][D_DIM];
    __shared__ float A_s [N_NODE][2 * N_NODE];
    __shared__ float ni_s[N_NODE][D_DIM];
    __shared__ float no_s[N_NODE][D_DIM];
    __shared__ float ii_s[N_NODE][D_DIM];
    __shared__ float io_s[N_NODE][D_DIM];
    __shared__ float wih_s[96][66];           // bank=(2d+k)%32 -> 2-way (free)
    __shared__ float whh_s[96][34];
    __shared__ float q1_s[D_DIM];
    __shared__ float alpha_s[L_SEQ];
    __shared__ int   last_s;

    // ---- P0: stage h (emb gather), A, and weights (all coalesced)
    for (int idx = tid; idx < 512; idx += 256) {
        const int n = idx >> 5, dd = idx & 31;
        const int it = items[b * N_NODE + n];
        h_s[n][dd] = emb[(size_t)it * D_DIM + dd];
        A_s[n][dd] = A[(size_t)b * 512 + idx];
    }
    for (int f = tid; f < 96 * 64; f += 256) wih_s[f >> 6][f & 63] = w_ih[f];
    for (int f = tid; f < 96 * 32; f += 256) whh_s[f >> 5][f & 31] = w_hh[f];
    __syncthreads();

    // ---- P1: node_in/node_out for n0, n1
    float ai0 = b_ein[d], ao0 = b_eout[d];
    float ai1 = ai0,      ao1 = ao0;
    #pragma unroll
    for (int k = 0; k < 32; ++k) {
        const float we = w_ein[k * 32 + d], wo = w_eout[k * 32 + d];
        const float h0 = h_s[n0][k], h1 = h_s[n1][k];
        ai0 += h0 * we; ai1 += h1 * we;
        ao0 += h0 * wo; ao1 += h1 * wo;
    }
    ni_s[n0][d] = ai0; ni_s[n1][d] = ai1;
    no_s[n0][d] = ao0; no_s[n1][d] = ao1;
    __syncthreads();

    // ---- P2: adjacency message passing
    float iv0 = b_iah[d], ov0 = b_oah[d];
    float iv1 = iv0,      ov1 = ov0;
    #pragma unroll
    for (int m = 0; m < N_NODE; ++m) {
        const float nim = ni_s[m][d], nom = no_s[m][d];
        iv0 += A_s[n0][m]          * nim;
        iv1 += A_s[n1][m]          * nim;
        ov0 += A_s[n0][N_NODE + m] * nom;
        ov1 += A_s[n1][N_NODE + m] * nom;
    }
    ii_s[n0][d] = iv0; ii_s[n1][d] = iv1;
    io_s[n0][d] = ov0; io_s[n1][d] = ov1;
    __syncthreads();

    // ---- P3 (fused gates): all operands from LDS
    float r0 = b_ih[d] + b_hh[d],           r1 = r0;
    float i0 = b_ih[32 + d] + b_hh[32 + d], i1 = i0;
    float gn0 = b_ih[64 + d],               gn1 = gn0;
    float hn0 = b_hh[64 + d],               hn1 = hn0;
    #pragma unroll
    for (int k = 0; k < 32; ++k) {
        const float wri = wih_s[d][k],      wro = wih_s[d][32 + k];
        const float wii = wih_s[32 + d][k], wio = wih_s[32 + d][32 + k];
        const float wni = wih_s[64 + d][k], wno = wih_s[64 + d][32 + k];
        const float whr = whh_s[d][k];
        const float whi = whh_s[32 + d][k];
        const float whn = whh_s[64 + d][k];
        const float a0 = ii_s[n0][k], a1 = ii_s[n1][k];
        const float o0 = io_s[n0][k], o1 = io_s[n1][k];
        const float h0 = h_s[n0][k],  h1 = h_s[n1][k];
        r0  += a0 * wri + o0 * wro + h0 * whr;
        r1  += a1 * wri + o1 * wro + h1 * whr;
        i0  += a0 * wii + o0 * wio + h0 * whi;
        i1  += a1 * wii + o1 * wio + h1 * whi;
        gn0 += a0 * wni + o0 * wno;
        gn1 += a1 * wni + o1 * wno;
        hn0 += h0 * whn;
        hn1 += h1 * whn;
    }

    // ---- P4: GRU nonlinearity, h update
    float hv0, hv1;
    {
        const float rg0 = sigf(r0), ig0 = sigf(i0);
        const float x0  = gn0 + rg0 * hn0;
        const float e0  = __expf(2.0f * fabsf(x0));
        const float ng0 = copysignf(1.0f - 2.0f / (e0 + 1.0f), x0);
        hv0 = ng0 + ig0 * (h_s[n0][d] - ng0);
        const float rg1 = sigf(r1), ig1 = sigf(i1);
        const float x1  = gn1 + rg1 * hn1;
        const float e1  = __expf(2.0f * fabsf(x1));
        const float ng1 = copysignf(1.0f - 2.0f / (e1 + 1.0f), x1);
        hv1 = ng1 + ig1 * (h_s[n1][d] - ng1);
    }
    __syncthreads();
    h_s[n0][d] = hv0;
    h_s[n1][d] = hv1;
    __syncthreads();

    // ---- P5: seq gather (into ni/no space) + last index
    for (int idx = tid; idx < L_SEQ * D_DIM; idx += 256) {
        const int t = idx >> 5, dd = idx & 31;
        const int a = alias_inputs[b * L_SEQ + t];
        const float v = h_s[a][dd];
        if (t < 16) ni_s[t][dd] = v;
        else        no_s[t - 16][dd] = v;
    }
    if (tid == 0) {
        int s = 0;
        for (int t = 0; t < L_SEQ; ++t) s += mask[b * L_SEQ + t];
        last_s = s - 1;
    }
    __syncthreads();

    // ---- P6: q1 = ht @ w1 + b1
    if (tid < D_DIM) {
        const int lt = last_s;
        const float* sl = (lt < 16) ? &ni_s[lt][0] : &no_s[lt - 16][0];
        float acc = b1[tid];
        #pragma unroll
        for (int k = 0; k < 32; ++k) acc += sl[k] * w1[k * 32 + tid];
        q1_s[tid] = acc;
    }
    __syncthreads();

    // ---- P7: alpha (tmp into ii/io space)
    for (int idx = tid; idx < L_SEQ * D_DIM; idx += 256) {
        const int t = idx >> 5, dd = idx & 31;
        const float* sp = (t < 16) ? &ni_s[t][0] : &no_s[t - 16][0];
        float q2 = b2[dd];
        #pragma unroll
        for (int k = 0; k < 32; ++k) q2 += sp[k] * w2[k * 32 + dd];
        const float val = sigf(q1_s[dd] + q2) * w3[dd];
        if (t < 16) ii_s[t][dd] = val;
        else        io_s[t - 16][dd] = val;
    }
    __syncthreads();
    if (tid < L_SEQ) {
        const float* tp = (tid < 16) ? &ii_s[tid][0] : &io_s[tid - 16][0];
        float a = 0.0f;
        #pragma unroll
        for (int dd = 0; dd < 32; ++dd) a += tp[dd];
        alpha_s[tid] = a * (float)mask[b * L_SEQ + tid];
    }
    __syncthreads();

    // ---- P8: s_g
    if (tid < D_DIM) {
        float acc = 0.0f;
        #pragma unroll
        for (int t = 0; t < L_SEQ; ++t) {
            const float sv = (t < 16) ? ni_s[t][tid] : no_s[t - 16][tid];
            acc += alpha_s[t] * sv;
        }
        sg_out[b * D_DIM + tid] = acc;
    }
}

// ---------------------------------------------------------------- kernel 2a
// VERBATIM r9 score3 (16-row tiles) — kept this round as the timing anchor.
__global__ __launch_bounds__(256) void score3_kernel(
    const float* __restrict__ sg,    // [4096, 32] f32 (ws)
    const float* __restrict__ emb,   // [50000, 32] f32
    float* __restrict__ out)         // [4096, 49999] f32
{
    __shared__ float eT[D_DIM][257];
    const int tid = threadIdx.x;
    const int b0  = blockIdx.x * 16;
    const int v0  = blockIdx.y * 256;

    #pragma unroll
    for (int i = 0; i < 8; ++i) {
        const int f = i * 256 + tid;
        const int r = f >> 3, c = f & 7;
        int grow = 1 + v0 + r;
        if (grow > NV_OUT) grow = NV_OUT;
        const f32x4 ev = *reinterpret_cast<const f32x4*>(
            &emb[(size_t)grow * D_DIM + c * 4]);
        eT[c * 4 + 0][r] = ev[0];
        eT[c * 4 + 1][r] = ev[1];
        eT[c * 4 + 2][r] = ev[2];
        eT[c * 4 + 3][r] = ev[3];
    }
    __syncthreads();

    float e[32];
    #pragma unroll
    for (int k = 0; k < 32; ++k) e[k] = eT[k][tid];

    const int  v  = v0 + tid;
    const bool ok = (v < NV_OUT);

    #pragma unroll
    for (int r = 0; r < 16; ++r) {
        const float* sr = sg + (size_t)(b0 + r) * D_DIM;
        float acc = 0.0f;
        #pragma unroll
        for (int k = 0; k < 32; ++k) acc += e[k] * sr[k];
        if (ok) out[(size_t)(b0 + r) * NV_OUT + v] = acc;
    }
}

// ---------------------------------------------------------------- kernel 2b
// score4: 32-row b-tiles. Identical arithmetic/order to score3 -> overwrites
// with the same values; this round's total minus 407us measures this kernel.
// Grid: (x = 128 b-tiles [fastest], y = 196 v-tiles).
__global__ __launch_bounds__(256) void score4_kernel(
    const float* __restrict__ sg,    // [4096, 32] f32 (ws)
    const float* __restrict__ emb,   // [50000, 32] f32
    float* __restrict__ out)         // [4096, 49999] f32
{
    __shared__ float eT[D_DIM][257];
    const int tid = threadIdx.x;
    const int b0  = blockIdx.x * 32;
    const int v0  = blockIdx.y * 256;

    #pragma unroll
    for (int i = 0; i < 8; ++i) {
        const int f = i * 256 + tid;
        const int r = f >> 3, c = f & 7;
        int grow = 1 + v0 + r;
        if (grow > NV_OUT) grow = NV_OUT;
        const f32x4 ev = *reinterpret_cast<const f32x4*>(
            &emb[(size_t)grow * D_DIM + c * 4]);
        eT[c * 4 + 0][r] = ev[0];
        eT[c * 4 + 1][r] = ev[1];
        eT[c * 4 + 2][r] = ev[2];
        eT[c * 4 + 3][r] = ev[3];
    }
    __syncthreads();

    float e[32];
    #pragma unroll
    for (int k = 0; k < 32; ++k) e[k] = eT[k][tid];

    const int  v  = v0 + tid;
    const bool ok = (v < NV_OUT);

    #pragma unroll
    for (int r = 0; r < 32; ++r) {
        const float* sr = sg + (size_t)(b0 + r) * D_DIM;   // block-uniform
        float acc = 0.0f;
        #pragma unroll
        for (int k = 0; k < 32; ++k) acc += e[k] * sr[k];
        if (ok) out[(size_t)(b0 + r) * NV_OUT + v] = acc;
    }
}

// ---------------------------------------------------------------- launch
extern "C" void kernel_launch(void* const* d_in, const int* in_sizes, int n_in,
                              void* d_out, int out_size, void* d_ws, size_t ws_size,
                              hipStream_t stream)
{
    const int*   alias_inputs = (const int*)  d_in[0];
    const float* A      = (const float*)d_in[1];
    const int*   items  = (const int*)  d_in[2];
    const int*   mask   = (const int*)  d_in[3];
    const float* emb    = (const float*)d_in[4];
    const float* w_ih   = (const float*)d_in[5];
    const float* w_hh   = (const float*)d_in[6];
    const float* b_ih   = (const float*)d_in[7];
    const float* b_hh   = (const float*)d_in[8];
    const float* b_iah  = (const float*)d_in[9];
    const float* b_oah  = (const float*)d_in[10];
    const float* w_ein  = (const float*)d_in[11];
    const float* b_ein  = (const float*)d_in[12];
    const float* w_eout = (const float*)d_in[13];
    const float* b_eout = (const float*)d_in[14];
    const float* w1     = (const float*)d_in[15];
    const float* b1     = (const float*)d_in[16];
    const float* w2     = (const float*)d_in[17];
    const float* b2     = (const float*)d_in[18];
    const float* w3     = (const float*)d_in[19];

    float* sg  = (float*)d_ws;                     // 4096*32 f32
    float* out = (float*)d_out;                    // FP32 output

    hipLaunchKernelGGL(session3_kernel, dim3(B_BATCH), dim3(256), 0, stream,
                       alias_inputs, A, items, mask, emb,
                       w_ih, w_hh, b_ih, b_hh, b_iah, b_oah,
                       w_ein, b_ein, w_eout, b_eout,
                       w1, b1, w2, b2, w3, sg);

    const int nvt = (NV_OUT + 255) / 256;   // 196
    hipLaunchKernelGGL(score3_kernel, dim3(B_BATCH / 16, nvt), dim3(256), 0, stream,
                       sg, emb, out);
    hipLaunchKernelGGL(score4_kernel, dim3(B_BATCH / 32, nvt), dim3(256), 0, stream,
                       sg, emb, out);
}

// Round 12
// 381.072 us; speedup vs baseline: 1.8065x; 1.8065x over previous
//
#include <hip/hip_runtime.h>

// SR-GNN session model, MI355X (gfx950). Inputs fp32/int32, output fp32.
// r12: score rebuilt around 4-v-per-thread amortization:
//   - transpose kernel: emb[50000][32] -> embT[32][50176] in ws (once, ~10us)
//   - score5: e4[k] loaded as aligned dwordx4 from embT (coalesced, L2-hit,
//     no per-block LDS staging); per b-row 8 broadcast ds_read_b128 of the
//     2KB sg tile feed 128 FMAs (4x the old 32) -> fetch:FMA 96:256 vs 96:64.
//   r11 measured score4 = 281us (issue-bound on per-row sr fetch); floor 126.
// session3 (r10) verbatim: ~95-120us by r10/r11 algebra.
//
// ws layout: [0) s_g 4096*32 f32 (512KB); [512KB) embT 32*50176 f32 (6.43MB)

#define B_BATCH 4096
#define N_NODE  16
#define L_SEQ   20
#define D_DIM   32
#define NV_OUT  49999
#define VT_STRIDE 50176   // 196*256, keeps embT rows 128B-aligned

typedef float f32x4  __attribute__((ext_vector_type(4)));
typedef float f32x4u __attribute__((ext_vector_type(4), aligned(4)));

__device__ __forceinline__ float sigf(float x) {
    return 1.0f / (1.0f + __expf(-x));
}

// ---------------------------------------------------------------- kernel 1
// One block per session; 256 threads = 8 node-groups x 32 d-lanes.
// VERBATIM r10 session3.
__global__ __launch_bounds__(256) void session3_kernel(
    const int*   __restrict__ alias_inputs,  // [B,20]
    const float* __restrict__ A,             // [B,16,32]
    const int*   __restrict__ items,         // [B,16]
    const int*   __restrict__ mask,          // [B,20]
    const float* __restrict__ emb,           // [V,32]
    const float* __restrict__ w_ih,          // [96,64]
    const float* __restrict__ w_hh,          // [96,32]
    const float* __restrict__ b_ih, const float* __restrict__ b_hh,
    const float* __restrict__ b_iah, const float* __restrict__ b_oah,
    const float* __restrict__ w_ein, const float* __restrict__ b_ein,
    const float* __restrict__ w_eout, const float* __restrict__ b_eout,
    const float* __restrict__ w1, const float* __restrict__ b1,
    const float* __restrict__ w2, const float* __restrict__ b2,
    const float* __restrict__ w3,
    float* __restrict__ sg_out)              // [B,32] fp32 (ws)
{
    const int b   = blockIdx.x;
    const int tid = threadIdx.x;
    const int g   = tid >> 5;      // node group 0..7
    const int d   = tid & 31;      // feature column
    const int n0  = g, n1 = g + 8;

    __shared__ float h_s [N_NODE][D_DIM];
    __shared__ float A_s [N_NODE][2 * N_NODE];
    __shared__ float ni_s[N_NODE][D_DIM];
    __shared__ float no_s[N_NODE][D_DIM];
    __shared__ float ii_s[N_NODE][D_DIM];
    __shared__ float io_s[N_NODE][D_DIM];
    __shared__ float wih_s[96][66];           // bank=(2d+k)%32 -> 2-way (free)
    __shared__ float whh_s[96][34];
    __shared__ float q1_s[D_DIM];
    __shared__ float alpha_s[L_SEQ];
    __shared__ int   last_s;

    // ---- P0: stage h (emb gather), A, and weights (all coalesced)
    for (int idx = tid; idx < 512; idx += 256) {
        const int n = idx >> 5, dd = idx & 31;
        const int it = items[b * N_NODE + n];
        h_s[n][dd] = emb[(size_t)it * D_DIM + dd];
        A_s[n][dd] = A[(size_t)b * 512 + idx];
    }
    for (int f = tid; f < 96 * 64; f += 256) wih_s[f >> 6][f & 63] = w_ih[f];
    for (int f = tid; f < 96 * 32; f += 256) whh_s[f >> 5][f & 31] = w_hh[f];
    __syncthreads();

    // ---- P1: node_in/node_out for n0, n1
    float ai0 = b_ein[d], ao0 = b_eout[d];
    float ai1 = ai0,      ao1 = ao0;
    #pragma unroll
    for (int k = 0; k < 32; ++k) {
        const float we = w_ein[k * 32 + d], wo = w_eout[k * 32 + d];
        const float h0 = h_s[n0][k], h1 = h_s[n1][k];
        ai0 += h0 * we; ai1 += h1 * we;
        ao0 += h0 * wo; ao1 += h1 * wo;
    }
    ni_s[n0][d] = ai0; ni_s[n1][d] = ai1;
    no_s[n0][d] = ao0; no_s[n1][d] = ao1;
    __syncthreads();

    // ---- P2: adjacency message passing
    float iv0 = b_iah[d], ov0 = b_oah[d];
    float iv1 = iv0,      ov1 = ov0;
    #pragma unroll
    for (int m = 0; m < N_NODE; ++m) {
        const float nim = ni_s[m][d], nom = no_s[m][d];
        iv0 += A_s[n0][m]          * nim;
        iv1 += A_s[n1][m]          * nim;
        ov0 += A_s[n0][N_NODE + m] * nom;
        ov1 += A_s[n1][N_NODE + m] * nom;
    }
    ii_s[n0][d] = iv0; ii_s[n1][d] = iv1;
    io_s[n0][d] = ov0; io_s[n1][d] = ov1;
    __syncthreads();

    // ---- P3 (fused gates): all operands from LDS
    float r0 = b_ih[d] + b_hh[d],           r1 = r0;
    float i0 = b_ih[32 + d] + b_hh[32 + d], i1 = i0;
    float gn0 = b_ih[64 + d],               gn1 = gn0;
    float hn0 = b_hh[64 + d],               hn1 = hn0;
    #pragma unroll
    for (int k = 0; k < 32; ++k) {
        const float wri = wih_s[d][k],      wro = wih_s[d][32 + k];
        const float wii = wih_s[32 + d][k], wio = wih_s[32 + d][32 + k];
        const float wni = wih_s[64 + d][k], wno = wih_s[64 + d][32 + k];
        const float whr = whh_s[d][k];
        const float whi = whh_s[32 + d][k];
        const float whn = whh_s[64 + d][k];
        const float a0 = ii_s[n0][k], a1 = ii_s[n1][k];
        const float o0 = io_s[n0][k], o1 = io_s[n1][k];
        const float h0 = h_s[n0][k],  h1 = h_s[n1][k];
        r0  += a0 * wri + o0 * wro + h0 * whr;
        r1  += a1 * wri + o1 * wro + h1 * whr;
        i0  += a0 * wii + o0 * wio + h0 * whi;
        i1  += a1 * wii + o1 * wio + h1 * whi;
        gn0 += a0 * wni + o0 * wno;
        gn1 += a1 * wni + o1 * wno;
        hn0 += h0 * whn;
        hn1 += h1 * whn;
    }

    // ---- P4: GRU nonlinearity, h update
    float hv0, hv1;
    {
        const float rg0 = sigf(r0), ig0 = sigf(i0);
        const float x0  = gn0 + rg0 * hn0;
        const float e0  = __expf(2.0f * fabsf(x0));
        const float ng0 = copysignf(1.0f - 2.0f / (e0 + 1.0f), x0);
        hv0 = ng0 + ig0 * (h_s[n0][d] - ng0);
        const float rg1 = sigf(r1), ig1 = sigf(i1);
        const float x1  = gn1 + rg1 * hn1;
        const float e1  = __expf(2.0f * fabsf(x1));
        const float ng1 = copysignf(1.0f - 2.0f / (e1 + 1.0f), x1);
        hv1 = ng1 + ig1 * (h_s[n1][d] - ng1);
    }
    __syncthreads();
    h_s[n0][d] = hv0;
    h_s[n1][d] = hv1;
    __syncthreads();

    // ---- P5: seq gather (into ni/no space) + last index
    for (int idx = tid; idx < L_SEQ * D_DIM; idx += 256) {
        const int t = idx >> 5, dd = idx & 31;
        const int a = alias_inputs[b * L_SEQ + t];
        const float v = h_s[a][dd];
        if (t < 16) ni_s[t][dd] = v;
        else        no_s[t - 16][dd] = v;
    }
    if (tid == 0) {
        int s = 0;
        for (int t = 0; t < L_SEQ; ++t) s += mask[b * L_SEQ + t];
        last_s = s - 1;
    }
    __syncthreads();

    // ---- P6: q1 = ht @ w1 + b1
    if (tid < D_DIM) {
        const int lt = last_s;
        const float* sl = (lt < 16) ? &ni_s[lt][0] : &no_s[lt - 16][0];
        float acc = b1[tid];
        #pragma unroll
        for (int k = 0; k < 32; ++k) acc += sl[k] * w1[k * 32 + tid];
        q1_s[tid] = acc;
    }
    __syncthreads();

    // ---- P7: alpha (tmp into ii/io space)
    for (int idx = tid; idx < L_SEQ * D_DIM; idx += 256) {
        const int t = idx >> 5, dd = idx & 31;
        const float* sp = (t < 16) ? &ni_s[t][0] : &no_s[t - 16][0];
        float q2 = b2[dd];
        #pragma unroll
        for (int k = 0; k < 32; ++k) q2 += sp[k] * w2[k * 32 + dd];
        const float val = sigf(q1_s[dd] + q2) * w3[dd];
        if (t < 16) ii_s[t][dd] = val;
        else        io_s[t - 16][dd] = val;
    }
    __syncthreads();
    if (tid < L_SEQ) {
        const float* tp = (tid < 16) ? &ii_s[tid][0] : &io_s[tid - 16][0];
        float a = 0.0f;
        #pragma unroll
        for (int dd = 0; dd < 32; ++dd) a += tp[dd];
        alpha_s[tid] = a * (float)mask[b * L_SEQ + tid];
    }
    __syncthreads();

    // ---- P8: s_g
    if (tid < D_DIM) {
        float acc = 0.0f;
        #pragma unroll
        for (int t = 0; t < L_SEQ; ++t) {
            const float sv = (t < 16) ? ni_s[t][tid] : no_s[t - 16][tid];
            acc += alpha_s[t] * sv;
        }
        sg_out[b * D_DIM + tid] = acc;
    }
}

// ---------------------------------------------------------------- kernel T
// embT[k][v] = emb[1+min(v,49998... clamp)][k], v in [0, 50176).
// LDS-tile transpose; both global sides coalesced. 196 blocks.
__global__ __launch_bounds__(256) void transpose_kernel(
    const float* __restrict__ emb, float* __restrict__ embT)
{
    __shared__ float eT[D_DIM][257];
    const int tid = threadIdx.x;
    const int v0  = blockIdx.x * 256;

    #pragma unroll
    for (int i = 0; i < 8; ++i) {
        const int f = i * 256 + tid;
        const int r = f >> 3, c = f & 7;
        int grow = 1 + v0 + r;
        if (grow > NV_OUT) grow = NV_OUT;      // emb row 49999 valid
        const f32x4 ev = *reinterpret_cast<const f32x4*>(
            &emb[(size_t)grow * D_DIM + c * 4]);
        eT[c * 4 + 0][r] = ev[0];
        eT[c * 4 + 1][r] = ev[1];
        eT[c * 4 + 2][r] = ev[2];
        eT[c * 4 + 3][r] = ev[3];
    }
    __syncthreads();

    #pragma unroll
    for (int k = 0; k < 32; ++k)
        embT[(size_t)k * VT_STRIDE + v0 + tid] = eT[k][tid];
}

// ---------------------------------------------------------------- kernel 2
// score5: 16 b-rows x 1024 v per block; thread owns 4 consecutive v.
// e4[k] from embT via aligned dwordx4 (coalesced 1KB/wave, L2-resident).
// Per row: 8 broadcast ds_read_b128 of sg tile -> 128 FMA -> dwordx4 store.
// Grid: (x = 256 b-tiles [fastest], y = 49 v-tiles).
__global__ __launch_bounds__(256) void score5_kernel(
    const float* __restrict__ sg,     // [4096, 32] f32 (ws)
    const float* __restrict__ embT,   // [32][VT_STRIDE] f32 (ws)
    float* __restrict__ out)          // [4096, 49999] f32
{
    __shared__ float sg_s[16][32];
    const int tid = threadIdx.x;
    const int b0  = blockIdx.x * 16;
    const int vq  = blockIdx.y * 1024 + tid * 4;   // my 4 v's: vq..vq+3

    if (tid < 128) {
        reinterpret_cast<f32x4*>(&sg_s[0][0])[tid] =
            reinterpret_cast<const f32x4*>(&sg[(size_t)b0 * D_DIM])[tid];
    }
    __syncthreads();

    f32x4 e4[32];
    #pragma unroll
    for (int k = 0; k < 32; ++k)
        e4[k] = *reinterpret_cast<const f32x4*>(&embT[(size_t)k * VT_STRIDE + vq]);

    const bool full = (vq + 3 < NV_OUT);

    #pragma unroll
    for (int r = 0; r < 16; ++r) {
        float sr[32];
        #pragma unroll
        for (int j = 0; j < 8; ++j)
            reinterpret_cast<f32x4*>(sr)[j] =
                *reinterpret_cast<const f32x4*>(&sg_s[r][j * 4]);  // broadcast
        f32x4 acc = {0.0f, 0.0f, 0.0f, 0.0f};
        #pragma unroll
        for (int k = 0; k < 32; ++k) acc += e4[k] * sr[k];
        float* op = out + (size_t)(b0 + r) * NV_OUT + vq;
        if (full) {
            *reinterpret_cast<f32x4u*>(op) = acc;
        } else {
            #pragma unroll
            for (int j = 0; j < 4; ++j)
                if (vq + j < NV_OUT) op[j] = acc[j];
        }
    }
}

// ---------------------------------------------------------------- kernel 2f
// Fallback (ws too small for embT): r11 score4, proven passing.
__global__ __launch_bounds__(256) void score4_kernel(
    const float* __restrict__ sg, const float* __restrict__ emb,
    float* __restrict__ out)
{
    __shared__ float eT[D_DIM][257];
    const int tid = threadIdx.x;
    const int b0  = blockIdx.x * 32;
    const int v0  = blockIdx.y * 256;

    #pragma unroll
    for (int i = 0; i < 8; ++i) {
        const int f = i * 256 + tid;
        const int r = f >> 3, c = f & 7;
        int grow = 1 + v0 + r;
        if (grow > NV_OUT) grow = NV_OUT;
        const f32x4 ev = *reinterpret_cast<const f32x4*>(
            &emb[(size_t)grow * D_DIM + c * 4]);
        eT[c * 4 + 0][r] = ev[0];
        eT[c * 4 + 1][r] = ev[1];
        eT[c * 4 + 2][r] = ev[2];
        eT[c * 4 + 3][r] = ev[3];
    }
    __syncthreads();

    float e[32];
    #pragma unroll
    for (int k = 0; k < 32; ++k) e[k] = eT[k][tid];

    const int  v  = v0 + tid;
    const bool ok = (v < NV_OUT);

    #pragma unroll
    for (int r = 0; r < 32; ++r) {
        const float* sr = sg + (size_t)(b0 + r) * D_DIM;
        float acc = 0.0f;
        #pragma unroll
        for (int k = 0; k < 32; ++k) acc += e[k] * sr[k];
        if (ok) out[(size_t)(b0 + r) * NV_OUT + v] = acc;
    }
}

// ---------------------------------------------------------------- launch
extern "C" void kernel_launch(void* const* d_in, const int* in_sizes, int n_in,
                              void* d_out, int out_size, void* d_ws, size_t ws_size,
                              hipStream_t stream)
{
    const int*   alias_inputs = (const int*)  d_in[0];
    const float* A      = (const float*)d_in[1];
    const int*   items  = (const int*)  d_in[2];
    const int*   mask   = (const int*)  d_in[3];
    const float* emb    = (const float*)d_in[4];
    const float* w_ih   = (const float*)d_in[5];
    const float* w_hh   = (const float*)d_in[6];
    const float* b_ih   = (const float*)d_in[7];
    const float* b_hh   = (const float*)d_in[8];
    const float* b_iah  = (const float*)d_in[9];
    const float* b_oah  = (const float*)d_in[10];
    const float* w_ein  = (const float*)d_in[11];
    const float* b_ein  = (const float*)d_in[12];
    const float* w_eout = (const float*)d_in[13];
    const float* b_eout = (const float*)d_in[14];
    const float* w1     = (const float*)d_in[15];
    const float* b1     = (const float*)d_in[16];
    const float* w2     = (const float*)d_in[17];
    const float* b2     = (const float*)d_in[18];
    const float* w3     = (const float*)d_in[19];

    float* sg   = (float*)d_ws;                            // 512 KB
    float* embT = (float*)((char*)d_ws + 512 * 1024);      // 6.43 MB
    float* out  = (float*)d_out;
    const size_t ws_need = 512 * 1024 + (size_t)32 * VT_STRIDE * 4;

    hipLaunchKernelGGL(session3_kernel, dim3(B_BATCH), dim3(256), 0, stream,
                       alias_inputs, A, items, mask, emb,
                       w_ih, w_hh, b_ih, b_hh, b_iah, b_oah,
                       w_ein, b_ein, w_eout, b_eout,
                       w1, b1, w2, b2, w3, sg);

    if (ws_size >= ws_need) {
        hipLaunchKernelGGL(transpose_kernel, dim3(VT_STRIDE / 256), dim3(256),
                           0, stream, emb, embT);
        hipLaunchKernelGGL(score5_kernel,
                           dim3(B_BATCH / 16, (NV_OUT + 1023) / 1024),
                           dim3(256), 0, stream, sg, embT, out);
    } else {
        hipLaunchKernelGGL(score4_kernel,
                           dim3(B_BATCH / 32, (NV_OUT + 255) / 256),
                           dim3(256), 0, stream, sg, emb, out);
    }
}